// Round 3
// baseline (510.887 us; speedup 1.0000x reference)
//
#include <hip/hip_runtime.h>

#define FEAT  125388
#define VEC4  (FEAT / 4)      // 31347 exactly (FEAT % 4 == 0)
#define L1    256
#define L2    32
#define L3    32
#define BATCH 1024
#define CAP   64              // >= ACTIVE(38); duplicates only shrink count

typedef unsigned int uint4_ev __attribute__((ext_vector_type(4)));

// One block per (position, perspective). Scan the sparse row (non-temporal,
// read-once), gather+sum W_in rows (values are exactly 1.0), clip, publish
// the 256-wide half of the concat vector. The LAST block of each pair to
// finish (device-scope atomic flag) runs the tail MLP inline.
__global__ __launch_bounds__(256) void nnue_fused(
    const float* __restrict__ x1, const float* __restrict__ x2,
    const float* __restrict__ W_in, const float* __restrict__ b_in,
    const float* __restrict__ W1, const float* __restrict__ b1,
    const float* __restrict__ W2, const float* __restrict__ b2,
    const float* __restrict__ Wo, const float* __restrict__ bo,
    float* __restrict__ x_cat,    // ws: [BATCH][2*L1]
    int*   __restrict__ flags,    // ws: [BATCH], zeroed each call
    float* __restrict__ out)
{
    const int bp = blockIdx.x;          // 0..2047
    const int b  = bp >> 1;
    const int p  = bp & 1;
    const int t  = threadIdx.x;

    __shared__ int   s_idx[CAP];
    __shared__ int   s_cnt;
    __shared__ int   s_last;
    __shared__ float s_x[2 * L1];
    __shared__ float s_part[8][L2];
    __shared__ float s_y[L2];
    __shared__ float s_o[L3];

    if (t == 0) s_cnt = 0;
    __syncthreads();

    // ---- Phase 1: coalesced nontemporal scan for nonzero features ----
    const float* base = (p == 0 ? x1 : x2) + (size_t)b * FEAT;
    const uint4_ev* row = reinterpret_cast<const uint4_ev*>(base);
    for (int iv = t; iv < VEC4; iv += 256) {
        uint4_ev v = __builtin_nontemporal_load(&row[iv]);
        if (v.x | v.y | v.z | v.w) {
            #pragma unroll
            for (int c = 0; c < 4; ++c) {
                if (v[c] != 0u) {
                    int slot = atomicAdd(&s_cnt, 1);
                    if (slot < CAP) s_idx[slot] = iv * 4 + c;
                }
            }
        }
    }
    __syncthreads();

    // ---- Phase 2: feature transformer (gather + sum + clip) ----
    const int n = min(s_cnt, CAP);
    float acc = b_in[t];
    for (int i = 0; i < n; ++i)
        acc += W_in[(size_t)s_idx[i] * L1 + t];   // coalesced 1 KB row reads
    const float v_own = fminf(fmaxf(acc, 0.f), 1.f);

    // ---- Publish own half; last-arriving block of the pair does the tail ----
    x_cat[(size_t)b * (2 * L1) + p * L1 + t] = v_own;
    __threadfence();                 // device-scope release of the store above
    __syncthreads();
    if (t == 0) {
        int old = __hip_atomic_fetch_add(&flags[b], 1, __ATOMIC_ACQ_REL,
                                         __HIP_MEMORY_SCOPE_AGENT);
        s_last = old;                // 1 => we arrived second
    }
    __syncthreads();
    if (s_last != 1) return;
    __threadfence();                 // device-scope acquire before reading sibling

    // ---- Phase 3: tail MLP (block-uniform path) ----
    s_x[p * L1 + t]       = v_own;
    s_x[(1 - p) * L1 + t] = x_cat[(size_t)b * (2 * L1) + (1 - p) * L1 + t];
    __syncthreads();

    {   // layer 1: [512] @ [512,32] — 8 k-chunks of 64, 32 outputs each
        const int j  = t & 31;
        const int pc = t >> 5;
        const int k0 = pc * 64;
        float a1 = 0.f;
        #pragma unroll 4
        for (int k = k0; k < k0 + 64; ++k)
            a1 += s_x[k] * W1[k * L2 + j];
        s_part[pc][j] = a1;
    }
    __syncthreads();
    if (t < L2) {
        float a1 = b1[t];
        #pragma unroll
        for (int pc = 0; pc < 8; ++pc) a1 += s_part[pc][t];
        s_y[t] = fminf(fmaxf(a1, 0.f), 1.f);
    }
    __syncthreads();
    if (t < L3) {
        float a2 = b2[t];
        #pragma unroll
        for (int k = 0; k < L2; ++k) a2 += s_y[k] * W2[k * L3 + t];
        s_o[t] = fminf(fmaxf(a2, 0.f), 1.f) * Wo[t];
    }
    __syncthreads();
    if (t == 0) {
        float a3 = bo[0];
        #pragma unroll
        for (int k = 0; k < L3; ++k) a3 += s_o[k];
        out[b] = a3;
    }
}

extern "C" void kernel_launch(void* const* d_in, const int* in_sizes, int n_in,
                              void* d_out, int out_size, void* d_ws, size_t ws_size,
                              hipStream_t stream) {
    const float* x1   = (const float*)d_in[0];
    const float* x2   = (const float*)d_in[1];
    const float* W_in = (const float*)d_in[2];
    const float* b_in = (const float*)d_in[3];
    const float* W1   = (const float*)d_in[4];
    const float* b1   = (const float*)d_in[5];
    const float* W2   = (const float*)d_in[6];
    const float* b2   = (const float*)d_in[7];
    const float* Wo   = (const float*)d_in[8];
    const float* bo   = (const float*)d_in[9];
    float* out   = (float*)d_out;

    float* x_cat = (float*)d_ws;                            // 2 MB
    int*   flags = (int*)((char*)d_ws + (size_t)BATCH * 2 * L1 * sizeof(float));

    hipMemsetAsync(flags, 0, BATCH * sizeof(int), stream);  // graph-capturable
    nnue_fused<<<2 * BATCH, 256, 0, stream>>>(
        x1, x2, W_in, b_in, W1, b1, W2, b2, Wo, bo, x_cat, flags, out);
}

// Round 4
// 193.972 us; speedup vs baseline: 2.6338x; 2.6338x over previous
//
#include <hip/hip_runtime.h>

#define FEAT  125388
#define VEC4  (FEAT / 4)      // 31347 exactly (FEAT % 4 == 0)
#define L1    256
#define L2    32
#define L3    32
#define BATCH 1024
#define CAP   64              // >= ACTIVE(38); duplicates only shrink count

typedef unsigned int uint4_ev __attribute__((ext_vector_type(4)));

__device__ __forceinline__ void scan_vec(uint4_ev v, int iv, int* s_idx, int* s_cnt) {
    if (v.x | v.y | v.z | v.w) {
        #pragma unroll
        for (int c = 0; c < 4; ++c) {
            if (v[c] != 0u) {
                int slot = atomicAdd(s_cnt, 1);
                if (slot < CAP) s_idx[slot] = iv * 4 + c;
            }
        }
    }
}

// ---------------- K1: one block per (position, perspective) ----------------
// Scan the sparse row with 4 outstanding nontemporal dwordx4 loads per thread
// (deep MLP toward the read BW ceiling), collect nonzero indices in LDS,
// gather+sum W_in rows (values are exactly 1.0), clip, write half-concat.
__global__ __launch_bounds__(256) void nnue_scan_ft(
    const float* __restrict__ x1, const float* __restrict__ x2,
    const float* __restrict__ W_in, const float* __restrict__ b_in,
    float* __restrict__ x_cat)   // [BATCH][2*L1]
{
    const int bp = blockIdx.x;          // 0..2047
    const int b  = bp >> 1;
    const int p  = bp & 1;
    const int t  = threadIdx.x;

    __shared__ int s_idx[CAP];
    __shared__ int s_cnt;
    if (t == 0) s_cnt = 0;
    __syncthreads();

    const float* base = (p == 0 ? x1 : x2) + (size_t)b * FEAT;
    const uint4_ev* row = reinterpret_cast<const uint4_ev*>(base);

    int iv = t;
    // 30 full unrolled iterations: 4 coalesced 4KB/wave loads in flight.
    for (; iv + 768 < VEC4; iv += 1024) {
        uint4_ev v0 = __builtin_nontemporal_load(&row[iv]);
        uint4_ev v1 = __builtin_nontemporal_load(&row[iv + 256]);
        uint4_ev v2 = __builtin_nontemporal_load(&row[iv + 512]);
        uint4_ev v3 = __builtin_nontemporal_load(&row[iv + 768]);
        scan_vec(v0, iv,       s_idx, &s_cnt);
        scan_vec(v1, iv + 256, s_idx, &s_cnt);
        scan_vec(v2, iv + 512, s_idx, &s_cnt);
        scan_vec(v3, iv + 768, s_idx, &s_cnt);
    }
    for (; iv < VEC4; iv += 256) {
        uint4_ev v = __builtin_nontemporal_load(&row[iv]);
        scan_vec(v, iv, s_idx, &s_cnt);
    }
    __syncthreads();

    // ---- feature transformer: gather + sum + clip (dual accumulators) ----
    const int n = min(s_cnt, CAP);
    float acc0 = b_in[t];
    float acc1 = 0.f;
    int i = 0;
    for (; i + 1 < n; i += 2) {
        acc0 += W_in[(size_t)s_idx[i]     * L1 + t];
        acc1 += W_in[(size_t)s_idx[i + 1] * L1 + t];
    }
    if (i < n) acc0 += W_in[(size_t)s_idx[i] * L1 + t];

    x_cat[(size_t)b * (2 * L1) + p * L1 + t] =
        fminf(fmaxf(acc0 + acc1, 0.f), 1.f);
}

// ---------------- K2: tail MLP, one block per position ----------------
__global__ __launch_bounds__(256) void nnue_tail(
    const float* __restrict__ x_cat,
    const float* __restrict__ W1, const float* __restrict__ b1,
    const float* __restrict__ W2, const float* __restrict__ b2,
    const float* __restrict__ Wo, const float* __restrict__ bo,
    float* __restrict__ out)
{
    const int b = blockIdx.x;
    const int t = threadIdx.x;

    __shared__ float s_x[2 * L1];
    __shared__ float s_part[8][L2];
    __shared__ float s_y[L2];
    __shared__ float s_o[L3];

    s_x[t]       = x_cat[(size_t)b * (2 * L1) + t];
    s_x[t + 256] = x_cat[(size_t)b * (2 * L1) + 256 + t];
    __syncthreads();

    // layer 1: [512] @ [512,32] — 8 k-chunks of 64, 32 outputs each
    {
        const int j  = t & 31;
        const int p  = t >> 5;
        const int k0 = p * 64;
        float acc = 0.f;
        #pragma unroll 4
        for (int k = k0; k < k0 + 64; ++k)
            acc += s_x[k] * W1[k * L2 + j];
        s_part[p][j] = acc;
    }
    __syncthreads();
    if (t < L2) {
        float acc = b1[t];
        #pragma unroll
        for (int p = 0; p < 8; ++p) acc += s_part[p][t];
        s_y[t] = fminf(fmaxf(acc, 0.f), 1.f);
    }
    __syncthreads();
    if (t < L3) {
        float acc = b2[t];
        #pragma unroll
        for (int k = 0; k < L2; ++k) acc += s_y[k] * W2[k * L3 + t];
        s_o[t] = fminf(fmaxf(acc, 0.f), 1.f) * Wo[t];
    }
    __syncthreads();
    if (t == 0) {
        float acc = bo[0];
        #pragma unroll
        for (int k = 0; k < L3; ++k) acc += s_o[k];
        out[b] = acc;
    }
}

extern "C" void kernel_launch(void* const* d_in, const int* in_sizes, int n_in,
                              void* d_out, int out_size, void* d_ws, size_t ws_size,
                              hipStream_t stream) {
    const float* x1   = (const float*)d_in[0];
    const float* x2   = (const float*)d_in[1];
    const float* W_in = (const float*)d_in[2];
    const float* b_in = (const float*)d_in[3];
    const float* W1   = (const float*)d_in[4];
    const float* b1   = (const float*)d_in[5];
    const float* W2   = (const float*)d_in[6];
    const float* b2   = (const float*)d_in[7];
    const float* Wo   = (const float*)d_in[8];
    const float* bo   = (const float*)d_in[9];
    float* out   = (float*)d_out;
    float* x_cat = (float*)d_ws;   // 2 MB, fully overwritten by K1 each call

    nnue_scan_ft<<<2 * BATCH, 256, 0, stream>>>(x1, x2, W_in, b_in, x_cat);
    nnue_tail<<<BATCH, 256, 0, stream>>>(x_cat, W1, b1, W2, b2, Wo, bo, out);
}

// Round 5
// 174.169 us; speedup vs baseline: 2.9333x; 1.1137x over previous
//
#include <hip/hip_runtime.h>

#define FEAT  125388
#define VEC4  (FEAT / 4)      // 31347 exactly (FEAT % 4 == 0)
#define L1    256
#define L2    32
#define L3    32
#define BATCH 1024
#define CAP   64              // >= ACTIVE(38); duplicates only shrink count

typedef unsigned int uint4_ev __attribute__((ext_vector_type(4)));

// One block (512 threads = 8 waves) per position: scan both perspective rows
// (R2's proven simple nontemporal loop), gather+sum W_in rows (values are
// exactly 1.0), clip, then run the tail MLP inline. 1024 blocks -> 4/CU ->
// 32 waves/CU (full occupancy). No cross-block communication.
__global__ __launch_bounds__(512) void nnue_fused_pos(
    const float* __restrict__ x1, const float* __restrict__ x2,
    const float* __restrict__ W_in, const float* __restrict__ b_in,
    const float* __restrict__ W1, const float* __restrict__ b1,
    const float* __restrict__ W2, const float* __restrict__ b2,
    const float* __restrict__ Wo, const float* __restrict__ bo,
    float* __restrict__ out)
{
    const int b = blockIdx.x;
    const int t = threadIdx.x;          // 0..511

    __shared__ int   s_idx[2][CAP];
    __shared__ int   s_cnt[2];
    __shared__ float s_x[2 * L1];       // clipped concat [512]
    __shared__ float s_part[16][L2];    // layer-1 partials (16 k-chunks of 32)
    __shared__ float s_y[L2];
    __shared__ float s_o[L3];

    if (t < 2) s_cnt[t] = 0;
    __syncthreads();

    // ---- Phase 1: scan both rows, 512-thread coalesced nontemporal loop ----
    #pragma unroll
    for (int p = 0; p < 2; ++p) {
        const float* base = (p == 0 ? x1 : x2) + (size_t)b * FEAT;
        const uint4_ev* row = reinterpret_cast<const uint4_ev*>(base);
        for (int iv = t; iv < VEC4; iv += 512) {
            uint4_ev v = __builtin_nontemporal_load(&row[iv]);
            if (v.x | v.y | v.z | v.w) {
                #pragma unroll
                for (int c = 0; c < 4; ++c) {
                    if (v[c] != 0u) {
                        int slot = atomicAdd(&s_cnt[p], 1);
                        if (slot < CAP) s_idx[p][slot] = iv * 4 + c;
                    }
                }
            }
        }
    }
    __syncthreads();

    // ---- Phase 2: feature transformer — halves gather in parallel ----
    {
        const int p   = t >> 8;         // 0: perspective 0, 1: perspective 1
        const int col = t & 255;
        const int n   = min(s_cnt[p], CAP);
        float acc = b_in[col];
        for (int i = 0; i < n; ++i)
            acc += W_in[(size_t)s_idx[p][i] * L1 + col];  // coalesced 1 KB rows
        s_x[p * L1 + col] = fminf(fmaxf(acc, 0.f), 1.f);
    }
    __syncthreads();

    // ---- Phase 3: tail MLP ----
    // layer 1: [512] @ [512,32] — 16 k-chunks of 32, 32 outputs each
    {
        const int j  = t & 31;
        const int pc = t >> 5;          // 0..15
        const int k0 = pc * 32;
        float acc = 0.f;
        #pragma unroll
        for (int k = k0; k < k0 + 32; ++k)
            acc += s_x[k] * W1[k * L2 + j];
        s_part[pc][j] = acc;
    }
    __syncthreads();
    if (t < L2) {
        float acc = b1[t];
        #pragma unroll
        for (int pc = 0; pc < 16; ++pc) acc += s_part[pc][t];
        s_y[t] = fminf(fmaxf(acc, 0.f), 1.f);
    }
    __syncthreads();
    if (t < L3) {
        float acc = b2[t];
        #pragma unroll
        for (int k = 0; k < L2; ++k) acc += s_y[k] * W2[k * L3 + t];
        s_o[t] = fminf(fmaxf(acc, 0.f), 1.f) * Wo[t];
    }
    __syncthreads();
    if (t == 0) {
        float acc = bo[0];
        #pragma unroll
        for (int k = 0; k < L3; ++k) acc += s_o[k];
        out[b] = acc;
    }
}

extern "C" void kernel_launch(void* const* d_in, const int* in_sizes, int n_in,
                              void* d_out, int out_size, void* d_ws, size_t ws_size,
                              hipStream_t stream) {
    const float* x1   = (const float*)d_in[0];
    const float* x2   = (const float*)d_in[1];
    const float* W_in = (const float*)d_in[2];
    const float* b_in = (const float*)d_in[3];
    const float* W1   = (const float*)d_in[4];
    const float* b1   = (const float*)d_in[5];
    const float* W2   = (const float*)d_in[6];
    const float* b2   = (const float*)d_in[7];
    const float* Wo   = (const float*)d_in[8];
    const float* bo   = (const float*)d_in[9];
    float* out = (float*)d_out;

    nnue_fused_pos<<<BATCH, 512, 0, stream>>>(
        x1, x2, W_in, b_in, W1, b1, W2, b2, Wo, bo, out);
}